// Round 7
// baseline (1153.250 us; speedup 1.0000x reference)
//
#include <hip/hip_runtime.h>
#include <math.h>

#define TT 256
#define HH 100
#define GG 400
#define BB 512

// ---- DPP quad-perm helpers (4-lane groups; VALU pipe) ----------------------
#define DPP_ROT1 147   // dest l <- src (l-1)&3 : perm [3,0,1,2]
#define DPP_ROT2 78    // dest l <- src (l-2)&3 : perm [2,3,0,1]
#define DPP_ROT3 57    // dest l <- src (l-3)&3 : perm [1,2,3,0]
#define DPP_XOR1 177   // perm [1,0,3,2]
#define DPP_XOR2 78    // perm [2,3,0,1]
#define DPP_XOR3 27    // perm [3,2,1,0]

template<int CTRL>
__device__ __forceinline__ float dppf(float v) {
    int i = __float_as_int(v);
    int r = __builtin_amdgcn_update_dpp(i, i, CTRL, 0xf, 0xf, false);
    return __int_as_float(r);
}

// arch-VGPR-pinned FMA: acc += w*h.  "v" excludes AGPRs -> allocator must keep
// hot operands in arch VGPRs (the AGPR-banking of the weight array in R4-R6 is
// what inflated VALU issue 2.7x).
#define VFMA(acc, w, h) \
    asm("v_fmac_f32 %0, %1, %2" : "+v"(acc) : "v"(w), "v"(h))

// LDS-drain-only barrier: keeps global loads/stores in flight
__device__ __forceinline__ void bar_lds() {
    asm volatile("s_waitcnt lgkmcnt(0)" ::: "memory");
    __builtin_amdgcn_s_barrier();
    asm volatile("" ::: "memory");
}

// ============================ recurrence kernel ==============================
// 512 blocks x 448 threads (7 waves; 400 active), 1 batch row/block,
// 2 blocks/CU (barriers interleave). Thread (u=tid>>2, ty=tid&3): k-quarter
// [25ty,25ty+25) partials for gates {((ty+d)&3)*100+u}; DPP-rotate combine.
// h double-buffered in LDS [2][4][28].
template<int LK>
__global__ void __launch_bounds__(448, 4)
lstm_recur(const float* __restrict__ x,        // [B][T][2]   (LK==0)
           const float* __restrict__ pre,      // [T*B][400]  (LK>=1, bias folded)
           const float* __restrict__ Whh,      // [400][100]
           const float* __restrict__ Wih0,     // [400][2]    (LK==0)
           const float* __restrict__ bih,      // [400]       (LK==0)
           const float* __restrict__ bhh,      // [400]       (LK==0)
           const float* __restrict__ head_w,   // [100]
           const float* __restrict__ head_b,   // [1]
           float* __restrict__ hs,             // [B][T][100] (LK<2 out)
           float* __restrict__ out)            // [B]         (LK==2 out)
{
    __shared__ float hbuf[2][4][28];   // [buf][quarter][25 used + 3 pad]

    const int tid = threadIdx.x;
    const int b   = blockIdx.x;        // one batch row per block
    const int u   = tid >> 2, ty = tid & 3;
    const int g   = ty * HH + u;       // own gate row
    const bool on = (tid < GG);

    // Wq[d][k] = Whh[((ty+d)&3)*100 + u][25*ty + k]
    float Wq[4][25];
    float w0a = 0.f, w0b = 0.f, bias = 0.f;
    if (on) {
        #pragma unroll
        for (int d = 0; d < 4; ++d) {
            const float* wrow = Whh + (((ty + d) & 3) * HH + u) * HH + 25 * ty;
            #pragma unroll
            for (int k = 0; k < 25; ++k) Wq[d][k] = wrow[k];
        }
        if (LK == 0) {
            w0a = Wih0[2 * g]; w0b = Wih0[2 * g + 1];
            bias = bih[g] + bhh[g];
        }
    }
    if (tid < 224) (&hbuf[0][0][0])[tid] = 0.f;   // zero both bufs incl. pads
    float c = 0.f;                                // ty==0 lanes own unit u's cell
    const int q_w = u / 25, i_w = u % 25;         // writer position
    __syncthreads();

    // prefetch t=0 input
    float p0 = 0.f;
    float2 xa = {0.f, 0.f};
    if (on) {
        if (LK == 0) xa = *(const float2*)(x + (size_t)b * TT * 2);
        else         p0 = pre[((size_t)0 * BB + b) * GG + g];
    }

    for (int t = 0; t < TT; ++t) {
        const int cur = t & 1, nxt = cur ^ 1;
        if (on) {
            float ext;
            if (LK == 0) ext = bias + w0a * xa.x + w0b * xa.y;
            else         ext = p0;

            // prefetch t+1 (stays in flight across the raw barrier)
            const int tn = (t + 1 < TT) ? t + 1 : t;
            if (LK == 0) xa = *(const float2*)(x + ((size_t)b * TT + tn) * 2);
            else         p0 = pre[((size_t)tn * BB + b) * GG + g];

            const float* hq = &hbuf[cur][ty][0];

            // software-pipelined chunked dot: live H regs <= 3 chunks (12)
            float pA = 0.f, pB = 0.f, pC = 0.f, pD = 0.f;
            float4 h0 = *(const float4*)(hq + 0);
            float4 h1 = *(const float4*)(hq + 4);
            #pragma unroll
            for (int i = 0; i < 6; ++i) {
                float4 hc = h0;
                h0 = h1;
                if (i < 5) h1 = *(const float4*)(hq + 4 * (i + 2));
                VFMA(pA, Wq[0][4*i+0], hc.x); VFMA(pB, Wq[1][4*i+0], hc.x);
                VFMA(pC, Wq[2][4*i+0], hc.x); VFMA(pD, Wq[3][4*i+0], hc.x);
                VFMA(pA, Wq[0][4*i+1], hc.y); VFMA(pB, Wq[1][4*i+1], hc.y);
                VFMA(pC, Wq[2][4*i+1], hc.y); VFMA(pD, Wq[3][4*i+1], hc.y);
                VFMA(pA, Wq[0][4*i+2], hc.z); VFMA(pB, Wq[1][4*i+2], hc.z);
                VFMA(pC, Wq[2][4*i+2], hc.z); VFMA(pD, Wq[3][4*i+2], hc.z);
                VFMA(pA, Wq[0][4*i+3], hc.w); VFMA(pB, Wq[1][4*i+3], hc.w);
                VFMA(pC, Wq[2][4*i+3], hc.w); VFMA(pD, Wq[3][4*i+3], hc.w);
            }
            const float hl = h0.x;   // k = 24 of the quarter
            VFMA(pA, Wq[0][24], hl); VFMA(pB, Wq[1][24], hl);
            VFMA(pC, Wq[2][24], hl); VFMA(pD, Wq[3][24], hl);

            // cross-quad combine: lane j gets gate-j partials from j-1,j-2,j-3
            float tot = pA + dppf<DPP_ROT1>(pB) + dppf<DPP_ROT2>(pC)
                           + dppf<DPP_ROT3>(pD) + ext;

            // activation by own role (ty==2 is the g-gate -> tanh)
            const bool isG = (ty == 2);
            float v = isG ? 2.f * tot : tot;
            float s = 1.f / (1.f + __expf(-v));
            if (isG) s = 2.f * s - 1.f;

            // gather the other three activated gates
            float B0 = dppf<DPP_XOR1>(s), C0 = dppf<DPP_XOR2>(s), D0 = dppf<DPP_XOR3>(s);

            if (ty == 0) {   // s=sig(i), B0=sig(f), C0=tanh(g), D0=sig(o)
                c = B0 * c + s * C0;
                float th = 2.f / (1.f + __expf(-2.f * c)) - 1.f;
                float hv = D0 * th;
                hbuf[nxt][q_w][i_w] = hv;
                if (LK < 2) hs[((size_t)b * TT + t) * HH + u] = hv;
            }
        }
        bar_lds();   // h(t) visible; orders hbuf[cur] reuse at t+1
    }

    // head: final h is in hbuf[0] (t=255 wrote nxt=0)
    if (LK == 2 && tid < 64) {
        const int lane = tid;
        float p = hbuf[0][lane / 25][lane % 25] * head_w[lane];
        if (lane < 36) {
            const int k2 = 64 + lane;
            p += hbuf[0][k2 / 25][k2 % 25] * head_w[k2];
        }
        #pragma unroll
        for (int off = 32; off; off >>= 1) p += __shfl_down(p, off);
        if (lane == 0) out[b] = p + head_b[0];
    }
}

// ============================ x-projection GEMM ==============================
// pre[row][g] = bias[g] + sum_k hs[b][t][k]*Wih[g][k], row = t*512+b.
// M=131072, N=400, K=100. block(320) = 64 rows x 80 gates, frag 4x4.
__global__ void __launch_bounds__(320, 2)
gemm_pre(const float* __restrict__ hs,     // [B][T][100]
         const float* __restrict__ Wih,    // [400][100]
         const float* __restrict__ bih,    // [400]
         const float* __restrict__ bhh,    // [400]
         float* __restrict__ pre)          // [M][400]
{
    __shared__ float A_s[100 * 64];        // k-major, swizzled
    __shared__ float W_s[100 * 80];        // k-major

    const int tid = threadIdx.x;
    const int ti  = tid / 20;              // 0..15 row group
    const int tj  = tid % 20;              // 0..19 gate group
    const int row0   = blockIdx.x * 64;    // 64 rows, same t (512%64==0)
    const int t      = row0 >> 9;
    const int b_base = row0 & 511;
    const int gbase  = blockIdx.y * 80;

    #pragma unroll
    for (int s = 0; s < 5; ++s) {
        const int L  = tid + 320 * s;
        const int r  = L / 25, kq = L % 25;
        float4 v = *(const float4*)(hs + ((size_t)(b_base + r) * TT + t) * HH + 4 * kq);
        const int r4 = r >> 2, rm = r & 3;
        A_s[(4*kq+0)*64 + (((r4) ^ (kq & 15)) << 2) + rm] = v.x;
        A_s[(4*kq+1)*64 + (((r4) ^ (kq & 15)) << 2) + rm] = v.y;
        A_s[(4*kq+2)*64 + (((r4) ^ (kq & 15)) << 2) + rm] = v.z;
        A_s[(4*kq+3)*64 + (((r4) ^ (kq & 15)) << 2) + rm] = v.w;
    }
    for (int L = tid; L < 2000; L += 320) {
        const int kq = L / 80, gl = L % 80;
        float4 v = *(const float4*)(Wih + (size_t)(gbase + gl) * HH + 4 * kq);
        W_s[(4*kq+0)*80 + gl] = v.x;
        W_s[(4*kq+1)*80 + gl] = v.y;
        W_s[(4*kq+2)*80 + gl] = v.z;
        W_s[(4*kq+3)*80 + gl] = v.w;
    }
    __syncthreads();

    float4 bs;
    {
        const float4 b1 = *(const float4*)(bih + gbase + 4 * tj);
        const float4 b2 = *(const float4*)(bhh + gbase + 4 * tj);
        bs.x = b1.x + b2.x; bs.y = b1.y + b2.y; bs.z = b1.z + b2.z; bs.w = b1.w + b2.w;
    }
    float acc[4][4];
    #pragma unroll
    for (int r = 0; r < 4; ++r) {
        acc[r][0] = bs.x; acc[r][1] = bs.y; acc[r][2] = bs.z; acc[r][3] = bs.w;
    }

    #pragma unroll 5
    for (int k4 = 0; k4 < 25; ++k4) {
        const int axo = ((ti ^ (k4 & 15)) << 2);
        float4 a[4], w[4];
        #pragma unroll
        for (int e = 0; e < 4; ++e) {
            a[e] = *(const float4*)&A_s[(4*k4+e)*64 + axo];
            w[e] = *(const float4*)&W_s[(4*k4+e)*80 + (tj << 2)];
        }
        #pragma unroll
        for (int e = 0; e < 4; ++e) {
            acc[0][0] += a[e].x * w[e].x; acc[0][1] += a[e].x * w[e].y;
            acc[0][2] += a[e].x * w[e].z; acc[0][3] += a[e].x * w[e].w;
            acc[1][0] += a[e].y * w[e].x; acc[1][1] += a[e].y * w[e].y;
            acc[1][2] += a[e].y * w[e].z; acc[1][3] += a[e].y * w[e].w;
            acc[2][0] += a[e].z * w[e].x; acc[2][1] += a[e].z * w[e].y;
            acc[2][2] += a[e].z * w[e].z; acc[2][3] += a[e].z * w[e].w;
            acc[3][0] += a[e].w * w[e].x; acc[3][1] += a[e].w * w[e].y;
            acc[3][2] += a[e].w * w[e].z; acc[3][3] += a[e].w * w[e].w;
        }
    }

    #pragma unroll
    for (int r = 0; r < 4; ++r) {
        const size_t row = row0 + 4 * ti + r;
        float4 v; v.x = acc[r][0]; v.y = acc[r][1]; v.z = acc[r][2]; v.w = acc[r][3];
        *(float4*)(pre + row * GG + gbase + 4 * tj) = v;
    }
}

// =============================================================================
extern "C" void kernel_launch(void* const* d_in, const int* in_sizes, int n_in,
                              void* d_out, int out_size, void* d_ws, size_t ws_size,
                              hipStream_t stream) {
    const float* x         = (const float*)d_in[0];
    const float* W_ih0     = (const float*)d_in[1];
    const float* W_ih_rest = (const float*)d_in[2];
    const float* W_hh      = (const float*)d_in[3];
    const float* b_ih      = (const float*)d_in[4];
    const float* b_hh      = (const float*)d_in[5];
    const float* head_w    = (const float*)d_in[6];
    const float* head_b    = (const float*)d_in[7];
    float* out = (float*)d_out;

    const size_t HS_BYTES = (size_t)BB * TT * HH * 4;   // 52.4 MB
    float* hs  = (float*)d_ws;
    float* pre = (float*)((char*)d_ws + HS_BYTES);      // 209.7 MB

    dim3 ggrid(2048, 5);

    lstm_recur<0><<<512, 448, 0, stream>>>(
        x, nullptr, W_hh, W_ih0, b_ih, b_hh, head_w, head_b, hs, out);

    gemm_pre<<<ggrid, 320, 0, stream>>>(hs, W_ih_rest, b_ih + GG, b_hh + GG, pre);
    lstm_recur<1><<<512, 448, 0, stream>>>(
        nullptr, pre, W_hh + 40000, nullptr, nullptr, nullptr, head_w, head_b, hs, out);

    gemm_pre<<<ggrid, 320, 0, stream>>>(hs, W_ih_rest + 40000, b_ih + 2*GG, b_hh + 2*GG, pre);
    lstm_recur<2><<<512, 448, 0, stream>>>(
        nullptr, pre, W_hh + 80000, nullptr, nullptr, nullptr, head_w, head_b, hs, out);
}

// Round 8
// 1051.552 us; speedup vs baseline: 1.0967x; 1.0967x over previous
//
#include <hip/hip_runtime.h>
#include <math.h>

#define TT 256
#define HH 100
#define GG 400
#define BB 512

// ---- DPP quad-perm helpers (4-lane groups; VALU pipe) ----------------------
#define DPP_ROT1 147   // dest l <- src (l-1)&3 : perm [3,0,1,2]
#define DPP_ROT2 78    // dest l <- src (l-2)&3 : perm [2,3,0,1]
#define DPP_ROT3 57    // dest l <- src (l-3)&3 : perm [1,2,3,0]
#define DPP_XOR1 177   // perm [1,0,3,2]
#define DPP_XOR2 78    // perm [2,3,0,1]
#define DPP_XOR3 27    // perm [3,2,1,0]

template<int CTRL>
__device__ __forceinline__ float dppf(float v) {
    int i = __float_as_int(v);
    int r = __builtin_amdgcn_update_dpp(i, i, CTRL, 0xf, 0xf, false);
    return __int_as_float(r);
}

// raw transcendental ops (1-ulp class; avoids IEEE div expansion)
__device__ __forceinline__ float fexp2(float x) {
    float r; asm("v_exp_f32 %0, %1" : "=v"(r) : "v"(x)); return r;
}
__device__ __forceinline__ float frcp(float x) {
    float r; asm("v_rcp_f32 %0, %1" : "=v"(r) : "v"(x)); return r;
}
#define LOG2E 1.44269504088896f
// sigmoid(x) = 1/(1+2^(-x*log2e));  tanh(x) = 2*sigmoid(2x)-1

// LDS-drain-only barrier: keeps global loads/stores in flight
__device__ __forceinline__ void bar_lds() {
    asm volatile("s_waitcnt lgkmcnt(0)" ::: "memory");
    __builtin_amdgcn_s_barrier();
    asm volatile("" ::: "memory");
}

// ============================ recurrence kernel ==============================
// 512 blocks x 448 threads (7 waves; 400 active), 1 batch row/block,
// 2 blocks/CU (barriers interleave). Thread (u=tid>>2, ty=tid&3): k-quarter
// [25ty,25ty+25) partials for gates {((ty+d)&3)*100+u}; DPP-rotate combine.
// h double-buffered in LDS [2][4][28].
// lb(448,3): VGPR cap 170 so the 100-float Wq stays in ARCH VGPRs (lb(...,4)'s
// 128 cap AGPR-banked it -> 2.4x VALU-issue inflation, R4-R7). 14 waves/CU
// still fit if actual usage <= 146.
template<int LK>
__global__ void __launch_bounds__(448, 3)
lstm_recur(const float* __restrict__ x,        // [B][T][2]   (LK==0)
           const float* __restrict__ pre,      // [T*B][400]  (LK>=1, bias folded)
           const float* __restrict__ Whh,      // [400][100]
           const float* __restrict__ Wih0,     // [400][2]    (LK==0)
           const float* __restrict__ bih,      // [400]       (LK==0)
           const float* __restrict__ bhh,      // [400]       (LK==0)
           const float* __restrict__ head_w,   // [100]
           const float* __restrict__ head_b,   // [1]
           float* __restrict__ hs,             // [B][T][100] (LK<2 out)
           float* __restrict__ out)            // [B]         (LK==2 out)
{
    __shared__ float hbuf[2][4][28];   // [buf][quarter][25 used + 3 pad]

    const int tid = threadIdx.x;
    const int b   = blockIdx.x;        // one batch row per block
    const int u   = tid >> 2, ty = tid & 3;
    const int g   = ty * HH + u;       // own gate row
    const bool on = (tid < GG);

    // Wq[d][k] = Whh[((ty+d)&3)*100 + u][25*ty + k]
    float Wq[4][25];
    float w0a = 0.f, w0b = 0.f, bias = 0.f;
    if (on) {
        #pragma unroll
        for (int d = 0; d < 4; ++d) {
            const float* wrow = Whh + (((ty + d) & 3) * HH + u) * HH + 25 * ty;
            #pragma unroll
            for (int k = 0; k < 25; ++k) Wq[d][k] = wrow[k];
        }
        if (LK == 0) {
            w0a = Wih0[2 * g]; w0b = Wih0[2 * g + 1];
            bias = bih[g] + bhh[g];
        }
    }
    if (tid < 224) (&hbuf[0][0][0])[tid] = 0.f;   // zero both bufs incl. pads
    float c = 0.f;                                // ty==0 lanes own unit u's cell
    const int q_w = u / 25, i_w = u % 25;         // writer position
    __syncthreads();

    // prefetch t=0 input
    float p0 = 0.f;
    float2 xa = {0.f, 0.f};
    if (on) {
        if (LK == 0) xa = *(const float2*)(x + (size_t)b * TT * 2);
        else         p0 = pre[((size_t)0 * BB + b) * GG + g];
    }

    for (int t = 0; t < TT; ++t) {
        const int cur = t & 1, nxt = cur ^ 1;
        if (on) {
            float ext;
            if (LK == 0) ext = bias + w0a * xa.x + w0b * xa.y;
            else         ext = p0;

            // prefetch t+1 (stays in flight across the raw barrier)
            const int tn = (t + 1 < TT) ? t + 1 : t;
            if (LK == 0) xa = *(const float2*)(x + ((size_t)b * TT + tn) * 2);
            else         p0 = pre[((size_t)tn * BB + b) * GG + g];

            const float4* hq = (const float4*)&hbuf[cur][ty][0];

            // plain unrolled dot; compiler schedules ds_reads + fmacs
            float pA = 0.f, pB = 0.f, pC = 0.f, pD = 0.f;
            #pragma unroll
            for (int i = 0; i < 6; ++i) {
                const float4 h4 = hq[i];
                pA += Wq[0][4*i+0] * h4.x; pB += Wq[1][4*i+0] * h4.x;
                pC += Wq[2][4*i+0] * h4.x; pD += Wq[3][4*i+0] * h4.x;
                pA += Wq[0][4*i+1] * h4.y; pB += Wq[1][4*i+1] * h4.y;
                pC += Wq[2][4*i+1] * h4.y; pD += Wq[3][4*i+1] * h4.y;
                pA += Wq[0][4*i+2] * h4.z; pB += Wq[1][4*i+2] * h4.z;
                pC += Wq[2][4*i+2] * h4.z; pD += Wq[3][4*i+2] * h4.z;
                pA += Wq[0][4*i+3] * h4.w; pB += Wq[1][4*i+3] * h4.w;
                pC += Wq[2][4*i+3] * h4.w; pD += Wq[3][4*i+3] * h4.w;
            }
            const float hl = hq[6].x;   // k = 24 of the quarter
            pA += Wq[0][24] * hl; pB += Wq[1][24] * hl;
            pC += Wq[2][24] * hl; pD += Wq[3][24] * hl;

            // cross-quad combine: lane j gets gate-j partials from j-1,j-2,j-3
            float tot = pA + dppf<DPP_ROT1>(pB) + dppf<DPP_ROT2>(pC)
                           + dppf<DPP_ROT3>(pD) + ext;

            // activation by own role (ty==2 is the g-gate -> tanh)
            const bool isG = (ty == 2);
            float v = isG ? 2.f * tot : tot;
            float s = frcp(1.f + fexp2(-LOG2E * v));
            if (isG) s = 2.f * s - 1.f;

            // gather the other three activated gates
            float B0 = dppf<DPP_XOR1>(s), C0 = dppf<DPP_XOR2>(s), D0 = dppf<DPP_XOR3>(s);

            if (ty == 0) {   // s=sig(i), B0=sig(f), C0=tanh(g), D0=sig(o)
                c = B0 * c + s * C0;
                float th = 2.f * frcp(1.f + fexp2(-2.f * LOG2E * c)) - 1.f;
                float hv = D0 * th;
                hbuf[nxt][q_w][i_w] = hv;
                if (LK < 2) hs[((size_t)b * TT + t) * HH + u] = hv;
            }
        }
        bar_lds();   // h(t) visible; orders hbuf[cur] reuse at t+1
    }

    // head: final h is in hbuf[0] (t=255 wrote nxt=0)
    if (LK == 2 && tid < 64) {
        const int lane = tid;
        float p = hbuf[0][lane / 25][lane % 25] * head_w[lane];
        if (lane < 36) {
            const int k2 = 64 + lane;
            p += hbuf[0][k2 / 25][k2 % 25] * head_w[k2];
        }
        #pragma unroll
        for (int off = 32; off; off >>= 1) p += __shfl_down(p, off);
        if (lane == 0) out[b] = p + head_b[0];
    }
}

// ============================ x-projection GEMM ==============================
// pre[row][g] = bias[g] + sum_k hs[b][t][k]*Wih[g][k], row = t*512+b.
// M=131072, N=400, K=100. block(320) = 64 rows x 80 gates, frag 4x4.
__global__ void __launch_bounds__(320, 2)
gemm_pre(const float* __restrict__ hs,     // [B][T][100]
         const float* __restrict__ Wih,    // [400][100]
         const float* __restrict__ bih,    // [400]
         const float* __restrict__ bhh,    // [400]
         float* __restrict__ pre)          // [M][400]
{
    __shared__ float A_s[100 * 64];        // k-major, swizzled
    __shared__ float W_s[100 * 80];        // k-major

    const int tid = threadIdx.x;
    const int ti  = tid / 20;              // 0..15 row group
    const int tj  = tid % 20;              // 0..19 gate group
    const int row0   = blockIdx.x * 64;    // 64 rows, same t (512%64==0)
    const int t      = row0 >> 9;
    const int b_base = row0 & 511;
    const int gbase  = blockIdx.y * 80;

    #pragma unroll
    for (int s = 0; s < 5; ++s) {
        const int L  = tid + 320 * s;
        const int r  = L / 25, kq = L % 25;
        float4 v = *(const float4*)(hs + ((size_t)(b_base + r) * TT + t) * HH + 4 * kq);
        const int r4 = r >> 2, rm = r & 3;
        A_s[(4*kq+0)*64 + (((r4) ^ (kq & 15)) << 2) + rm] = v.x;
        A_s[(4*kq+1)*64 + (((r4) ^ (kq & 15)) << 2) + rm] = v.y;
        A_s[(4*kq+2)*64 + (((r4) ^ (kq & 15)) << 2) + rm] = v.z;
        A_s[(4*kq+3)*64 + (((r4) ^ (kq & 15)) << 2) + rm] = v.w;
    }
    for (int L = tid; L < 2000; L += 320) {
        const int kq = L / 80, gl = L % 80;
        float4 v = *(const float4*)(Wih + (size_t)(gbase + gl) * HH + 4 * kq);
        W_s[(4*kq+0)*80 + gl] = v.x;
        W_s[(4*kq+1)*80 + gl] = v.y;
        W_s[(4*kq+2)*80 + gl] = v.z;
        W_s[(4*kq+3)*80 + gl] = v.w;
    }
    __syncthreads();

    float4 bs;
    {
        const float4 b1 = *(const float4*)(bih + gbase + 4 * tj);
        const float4 b2 = *(const float4*)(bhh + gbase + 4 * tj);
        bs.x = b1.x + b2.x; bs.y = b1.y + b2.y; bs.z = b1.z + b2.z; bs.w = b1.w + b2.w;
    }
    float acc[4][4];
    #pragma unroll
    for (int r = 0; r < 4; ++r) {
        acc[r][0] = bs.x; acc[r][1] = bs.y; acc[r][2] = bs.z; acc[r][3] = bs.w;
    }

    #pragma unroll 5
    for (int k4 = 0; k4 < 25; ++k4) {
        const int axo = ((ti ^ (k4 & 15)) << 2);
        float4 a[4], w[4];
        #pragma unroll
        for (int e = 0; e < 4; ++e) {
            a[e] = *(const float4*)&A_s[(4*k4+e)*64 + axo];
            w[e] = *(const float4*)&W_s[(4*k4+e)*80 + (tj << 2)];
        }
        #pragma unroll
        for (int e = 0; e < 4; ++e) {
            acc[0][0] += a[e].x * w[e].x; acc[0][1] += a[e].x * w[e].y;
            acc[0][2] += a[e].x * w[e].z; acc[0][3] += a[e].x * w[e].w;
            acc[1][0] += a[e].y * w[e].x; acc[1][1] += a[e].y * w[e].y;
            acc[1][2] += a[e].y * w[e].z; acc[1][3] += a[e].y * w[e].w;
            acc[2][0] += a[e].z * w[e].x; acc[2][1] += a[e].z * w[e].y;
            acc[2][2] += a[e].z * w[e].z; acc[2][3] += a[e].z * w[e].w;
            acc[3][0] += a[e].w * w[e].x; acc[3][1] += a[e].w * w[e].y;
            acc[3][2] += a[e].w * w[e].z; acc[3][3] += a[e].w * w[e].w;
        }
    }

    #pragma unroll
    for (int r = 0; r < 4; ++r) {
        const size_t row = row0 + 4 * ti + r;
        float4 v; v.x = acc[r][0]; v.y = acc[r][1]; v.z = acc[r][2]; v.w = acc[r][3];
        *(float4*)(pre + row * GG + gbase + 4 * tj) = v;
    }
}

// =============================================================================
extern "C" void kernel_launch(void* const* d_in, const int* in_sizes, int n_in,
                              void* d_out, int out_size, void* d_ws, size_t ws_size,
                              hipStream_t stream) {
    const float* x         = (const float*)d_in[0];
    const float* W_ih0     = (const float*)d_in[1];
    const float* W_ih_rest = (const float*)d_in[2];
    const float* W_hh      = (const float*)d_in[3];
    const float* b_ih      = (const float*)d_in[4];
    const float* b_hh      = (const float*)d_in[5];
    const float* head_w    = (const float*)d_in[6];
    const float* head_b    = (const float*)d_in[7];
    float* out = (float*)d_out;

    const size_t HS_BYTES = (size_t)BB * TT * HH * 4;   // 52.4 MB
    float* hs  = (float*)d_ws;
    float* pre = (float*)((char*)d_ws + HS_BYTES);      // 209.7 MB

    dim3 ggrid(2048, 5);

    lstm_recur<0><<<512, 448, 0, stream>>>(
        x, nullptr, W_hh, W_ih0, b_ih, b_hh, head_w, head_b, hs, out);

    gemm_pre<<<ggrid, 320, 0, stream>>>(hs, W_ih_rest, b_ih + GG, b_hh + GG, pre);
    lstm_recur<1><<<512, 448, 0, stream>>>(
        nullptr, pre, W_hh + 40000, nullptr, nullptr, nullptr, head_w, head_b, hs, out);

    gemm_pre<<<ggrid, 320, 0, stream>>>(hs, W_ih_rest + 40000, b_ih + 2*GG, b_hh + 2*GG, pre);
    lstm_recur<2><<<512, 448, 0, stream>>>(
        nullptr, pre, W_hh + 80000, nullptr, nullptr, nullptr, head_w, head_b, hs, out);
}